// Round 3
// baseline (221.743 us; speedup 1.0000x reference)
//
#include <hip/hip_runtime.h>

// VectorQuantizer: x [16,4096,256] f32, embedding [1024,256] f32
// outputs (concat): quantized_st [16,4096,256] f32, loss f32, perplexity f32
// M = 65536 rows, N = 1024 codes, E = 256 dims.
//
// ws layout:
//   idx       : int[65536]      @ 0       (256 KiB)
//   en2h      : float[1024]     @ 262144  (4 KiB)   holds -||e||^2 / 2
//   embB      : ushort[262144]  @ 266240  (512 KiB) bf16 embedding
//   counts    : uint[1024]      @ 790528  (4 KiB)
//   loss_part : double[256]     @ 794624  (2 KiB)

#define VQ_M 65536
#define VQ_N 1024
#define VQ_E 256

typedef __attribute__((ext_vector_type(8))) short bf16x8;
typedef __attribute__((ext_vector_type(4))) float f32x4;

// float -> bf16 round-to-nearest-even (bit trick; NaN irrelevant here)
__device__ __forceinline__ ushort f2b(float f) {
  unsigned u = __float_as_uint(f);
  return (ushort)((u + 0x7FFFu + ((u >> 16) & 1u)) >> 16);
}

// ---------------------------------------------------------------- kernel A
// en2h = -||e_n||^2/2 (fp64 reduce, fp32 store), emb -> bf16, zero counts.
__global__ __launch_bounds__(256) void vq_prep(
    const float* __restrict__ emb, float* __restrict__ en2h,
    ushort* __restrict__ embB, unsigned* __restrict__ counts) {
  const int tid  = threadIdx.x;
  const int lane = tid & 63;
  const int n    = blockIdx.x * 4 + (tid >> 6);   // 256 blocks * 4 waves
  const float4 e4 = reinterpret_cast<const float4*>(emb)[n * 64 + lane];
  double s = (double)e4.x * e4.x + (double)e4.y * e4.y +
             (double)e4.z * e4.z + (double)e4.w * e4.w;
#pragma unroll
  for (int m = 1; m < 64; m <<= 1) s += __shfl_xor(s, m, 64);
  if (lane == 0) en2h[n] = (float)(-0.5 * s);
  ushort4 b;
  b.x = f2b(e4.x); b.y = f2b(e4.y); b.z = f2b(e4.z); b.w = f2b(e4.w);
  reinterpret_cast<ushort4*>(embB)[n * 64 + lane] = b;
  if (blockIdx.x == 0) {
#pragma unroll
    for (int j = 0; j < 4; ++j) counts[tid + j * 256] = 0u;
  }
}

// ---------------------------------------------------------------- kernel B
// Fused argmin + loss partial + histogram.
// D[code][xrow] = Emb . X^T via mfma_16x16x32_bf16, acc init = -||e||^2/2,
// argmin(dist) == argmax(acc); loss_row = ||x||^2 - 2*max(acc).
// Wave owns 64 x-rows in registers (fx=4); block = 4 waves = 256 rows;
// grid = 256 blocks (1/CU). Emb streams as [64 codes][128 k] bf16 half-
// chunks through double-buffered LDS (16 KiB each) with XOR granule
// swizzle; kh halves are statically unrolled so xf/buffer indices are
// compile-time (no scratch).
__global__ __launch_bounds__(256, 1) void vq_argmin_mfma(
    const float* __restrict__ X, const ushort* __restrict__ embB,
    const float* __restrict__ en2h, int* __restrict__ idxOut,
    unsigned* __restrict__ counts, double* __restrict__ loss_part) {
  __shared__ ushort lds[2][64 * 128];   // 2 x 16 KiB
  __shared__ float shl[4];
  const int tid = threadIdx.x;
  const int w  = tid >> 6;
  const int l  = tid & 63;
  const int lr = l & 15;
  const int g4 = l >> 4;
  const int m0 = blockIdx.x * 256;
  const float4* __restrict__ embB4 = reinterpret_cast<const float4*>(embB);

  // staging granule coords: 1024 granules of 16B per half-chunk, 4/thread
  int grow[4], gcol[4];
#pragma unroll
  for (int i = 0; i < 4; ++i) {
    const int gg = tid + 256 * i;
    grow[i] = gg >> 4;        // code row 0..63
    gcol[i] = gg & 15;        // 16B granule col 0..15 (128 k = 256B/row)
  }

  // prologue: stage chunk (nt=0, kh=0) into lds[0]
  {
    float4 s[4];
#pragma unroll
    for (int i = 0; i < 4; ++i) s[i] = embB4[grow[i] * 32 + gcol[i]];
#pragma unroll
    for (int i = 0; i < 4; ++i)
      reinterpret_cast<float4*>(lds[0])[grow[i] * 16 +
                                        (gcol[i] ^ (grow[i] & 15))] = s[i];
  }

  // X prologue: f32 load (read once), ||x||^2, bf16 pack.
  // row = m0 + w*64 + fx*16 + lr;  k = kc*32 + g4*8 .. +8
  bf16x8 xf[4][8];
  float sx[4];
#pragma unroll
  for (int fx = 0; fx < 4; ++fx) {
    sx[fx] = 0.0f;
    const float* rowp =
        X + (size_t)(m0 + w * 64 + fx * 16 + lr) * 256 + g4 * 8;
#pragma unroll
    for (int kc = 0; kc < 8; ++kc) {
      const float4 a = *reinterpret_cast<const float4*>(rowp + kc * 32);
      const float4 b = *reinterpret_cast<const float4*>(rowp + kc * 32 + 4);
      sx[fx] += a.x * a.x + a.y * a.y + a.z * a.z + a.w * a.w +
                b.x * b.x + b.y * b.y + b.z * b.z + b.w * b.w;
      bf16x8 v;
      v[0] = (short)f2b(a.x); v[1] = (short)f2b(a.y);
      v[2] = (short)f2b(a.z); v[3] = (short)f2b(a.w);
      v[4] = (short)f2b(b.x); v[5] = (short)f2b(b.y);
      v[6] = (short)f2b(b.z); v[7] = (short)f2b(b.w);
      xf[fx][kc] = v;
    }
  }
  __syncthreads();

  float bval[4];
  int   bidx[4];
#pragma unroll
  for (int fx = 0; fx < 4; ++fx) { bval[fx] = -3.4e38f; bidx[fx] = 0; }

  for (int nt = 0; nt < 16; ++nt) {
    f32x4 acc[4][4];
    float4 s[4];

    // -------- half 0: compute lds[0] (k 0..127); prefetch (nt,1) -> lds[1]
#pragma unroll
    for (int i = 0; i < 4; ++i)
      s[i] = embB4[(nt * 64 + grow[i]) * 32 + 16 + gcol[i]];
#pragma unroll
    for (int cf = 0; cf < 4; ++cf) {
      const f32x4 e2 =
          *reinterpret_cast<const f32x4*>(en2h + nt * 64 + cf * 16 + g4 * 4);
#pragma unroll
      for (int fx = 0; fx < 4; ++fx) acc[cf][fx] = e2;
    }
#pragma unroll
    for (int kc = 0; kc < 4; ++kc) {
      bf16x8 af[4];
#pragma unroll
      for (int cf = 0; cf < 4; ++cf)
        af[cf] = *reinterpret_cast<const bf16x8*>(
            &lds[0][((cf * 16 + lr) * 16 + ((kc * 4 + g4) ^ lr)) * 8]);
#pragma unroll
      for (int cf = 0; cf < 4; ++cf)
#pragma unroll
        for (int fx = 0; fx < 4; ++fx)
          acc[cf][fx] = __builtin_amdgcn_mfma_f32_16x16x32_bf16(
              af[cf], xf[fx][kc], acc[cf][fx], 0, 0, 0);
    }
#pragma unroll
    for (int i = 0; i < 4; ++i)
      reinterpret_cast<float4*>(lds[1])[grow[i] * 16 +
                                        (gcol[i] ^ (grow[i] & 15))] = s[i];
    __syncthreads();

    // -------- half 1: compute lds[1] (k 128..255); prefetch (nt+1,0)->lds[0]
    if (nt < 15) {
#pragma unroll
      for (int i = 0; i < 4; ++i)
        s[i] = embB4[((nt + 1) * 64 + grow[i]) * 32 + gcol[i]];
    }
#pragma unroll
    for (int kc = 0; kc < 4; ++kc) {
      bf16x8 af[4];
#pragma unroll
      for (int cf = 0; cf < 4; ++cf)
        af[cf] = *reinterpret_cast<const bf16x8*>(
            &lds[1][((cf * 16 + lr) * 16 + ((kc * 4 + g4) ^ lr)) * 8]);
#pragma unroll
      for (int cf = 0; cf < 4; ++cf)
#pragma unroll
        for (int fx = 0; fx < 4; ++fx)
          acc[cf][fx] = __builtin_amdgcn_mfma_f32_16x16x32_bf16(
              af[cf], xf[fx][4 + kc], acc[cf][fx], 0, 0, 0);
    }
    // fold into running argmax (ascending code order; strict > keeps first)
#pragma unroll
    for (int cf = 0; cf < 4; ++cf)
#pragma unroll
      for (int fx = 0; fx < 4; ++fx)
#pragma unroll
        for (int q = 0; q < 4; ++q) {
          const float v = acc[cf][fx][q];
          const int code = nt * 64 + cf * 16 + g4 * 4 + q;
          if (v > bval[fx]) { bval[fx] = v; bidx[fx] = code; }
        }
    if (nt < 15) {
#pragma unroll
      for (int i = 0; i < 4; ++i)
        reinterpret_cast<float4*>(lds[0])[grow[i] * 16 +
                                          (gcol[i] ^ (grow[i] & 15))] = s[i];
      __syncthreads();
    }
  }

  // merge (val,idx) and sum sx across the 4 lane-groups of each xrow
#pragma unroll
  for (int off = 16; off <= 32; off <<= 1)
#pragma unroll
    for (int fx = 0; fx < 4; ++fx) {
      const float ov = __shfl_xor(bval[fx], off, 64);
      const int   oi = __shfl_xor(bidx[fx], off, 64);
      if (ov > bval[fx] || (ov == bval[fx] && oi < bidx[fx])) {
        bval[fx] = ov;
        bidx[fx] = oi;
      }
      sx[fx] += __shfl_xor(sx[fx], off, 64);
    }

  float lloss = 0.0f;
  if (g4 == 0) {
#pragma unroll
    for (int fx = 0; fx < 4; ++fx) {
      idxOut[m0 + w * 64 + fx * 16 + lr] = bidx[fx];
      atomicAdd(&counts[bidx[fx]], 1u);
      lloss += sx[fx] - 2.0f * bval[fx];   // = ||x||^2 + dist
    }
  }
  // sum over the 16 lr lanes (other quarters contribute 0)
#pragma unroll
  for (int off = 1; off < 16; off <<= 1) lloss += __shfl_xor(lloss, off, 64);
  if (l == 0) shl[w] = lloss;
  __syncthreads();
  if (tid == 0)
    loss_part[blockIdx.x] =
        (double)shl[0] + (double)shl[1] + (double)shl[2] + (double)shl[3];
}

// ---------------------------------------------------------------- kernel C
// out = embedding[idx]  (== x + (q - x) within 1-2 ulp)
__global__ __launch_bounds__(256) void vq_gather(
    const int* __restrict__ idx, const float* __restrict__ Emb,
    float* __restrict__ out) {
  const int F4 = VQ_M * 64;
  const int stride = gridDim.x * 256;
  for (int i = blockIdx.x * 256 + threadIdx.x; i < F4; i += stride) {
    const int c = idx[i >> 6];
    reinterpret_cast<float4*>(out)[i] =
        reinterpret_cast<const float4*>(Emb)[c * 64 + (i & 63)];
  }
}

// ---------------------------------------------------------------- kernel D
// loss = 1.25 * sum(loss_part)/16.7M; perplexity = exp(-sum p log(p+1e-10))
__global__ __launch_bounds__(1024) void vq_final(
    const unsigned* __restrict__ counts, const double* __restrict__ loss_part,
    float* __restrict__ out) {
  const int tid = threadIdx.x;  // 1024 threads
  const double p = (double)counts[tid] * (1.0 / 65536.0);
  double term = -p * log(p + 1e-10);
  double lp = (tid < 256) ? loss_part[tid] : 0.0;
#pragma unroll
  for (int m = 1; m < 64; m <<= 1) {
    term += __shfl_xor(term, m, 64);
    lp   += __shfl_xor(lp, m, 64);
  }
  __shared__ double sh[16], sl[16];
  if ((tid & 63) == 0) { sh[tid >> 6] = term; sl[tid >> 6] = lp; }
  __syncthreads();
  if (tid == 0) {
    double H = 0.0, L = 0.0;
#pragma unroll
    for (int i = 0; i < 16; ++i) { H += sh[i]; L += sl[i]; }
    out[16777216] = (float)(1.25 * L * (1.0 / 16777216.0));
    out[16777217] = (float)exp(H);
  }
}

// ---------------------------------------------------------------- launch
extern "C" void kernel_launch(void* const* d_in, const int* in_sizes, int n_in,
                              void* d_out, int out_size, void* d_ws, size_t ws_size,
                              hipStream_t stream) {
  const float* X   = (const float*)d_in[0];
  const float* Emb = (const float*)d_in[1];
  float* out = (float*)d_out;
  char* ws = (char*)d_ws;
  int*      idx       = (int*)(ws);
  float*    en2h      = (float*)(ws + 262144);
  ushort*   embB      = (ushort*)(ws + 266240);
  unsigned* counts    = (unsigned*)(ws + 790528);
  double*   loss_part = (double*)(ws + 794624);

  vq_prep<<<256, 256, 0, stream>>>(Emb, en2h, embB, counts);
  vq_argmin_mfma<<<256, 256, 0, stream>>>(X, embB, en2h, idx, counts, loss_part);
  vq_gather<<<2048, 256, 0, stream>>>(idx, Emb, out);
  vq_final<<<1, 1024, 0, stream>>>(counts, loss_part, out);
}

// Round 4
// 175.434 us; speedup vs baseline: 1.2640x; 1.2640x over previous
//
#include <hip/hip_runtime.h>

// VectorQuantizer: x [16,4096,256] f32, embedding [1024,256] f32
// outputs (concat): quantized_st [16,4096,256] f32, loss f32, perplexity f32
// M = 65536 rows, N = 1024 codes, E = 256 dims.
//
// ws layout:
//   en2h      : float[1024]     @ 0       (4 KiB)   holds -||e||^2 / 2
//   embB      : ushort[262144]  @ 4096    (512 KiB) bf16 embedding
//   counts    : uint[1024]      @ 528384  (4 KiB)
//   loss_part : double[256]     @ 532480  (2 KiB)

#define VQ_M 65536
#define VQ_N 1024
#define VQ_E 256

typedef __attribute__((ext_vector_type(8)))  short bf16x8;
typedef __attribute__((ext_vector_type(4)))  float f32x4;
typedef __attribute__((ext_vector_type(16))) float f32x16;

// float -> bf16 round-to-nearest-even
__device__ __forceinline__ ushort f2b(float f) {
  unsigned u = __float_as_uint(f);
  return (ushort)((u + 0x7FFFu + ((u >> 16) & 1u)) >> 16);
}

// async global->LDS, 16B per lane; LDS dest = wave-uniform base + lane*16
__device__ __forceinline__ void gl_lds16(const void* g, void* l) {
  __builtin_amdgcn_global_load_lds(
      (const __attribute__((address_space(1))) unsigned int*)g,
      (__attribute__((address_space(3))) unsigned int*)l, 16, 0, 0);
}

// ---------------------------------------------------------------- kernel A
// en2h = -||e_n||^2/2 (fp64 reduce), emb -> bf16, zero counts.
__global__ __launch_bounds__(256) void vq_prep(
    const float* __restrict__ emb, float* __restrict__ en2h,
    ushort* __restrict__ embB, unsigned* __restrict__ counts) {
  const int tid  = threadIdx.x;
  const int lane = tid & 63;
  const int n    = blockIdx.x * 4 + (tid >> 6);   // 256 blocks * 4 waves
  const float4 e4 = reinterpret_cast<const float4*>(emb)[n * 64 + lane];
  double s = (double)e4.x * e4.x + (double)e4.y * e4.y +
             (double)e4.z * e4.z + (double)e4.w * e4.w;
#pragma unroll
  for (int m = 1; m < 64; m <<= 1) s += __shfl_xor(s, m, 64);
  if (lane == 0) en2h[n] = (float)(-0.5 * s);
  ushort4 b;
  b.x = f2b(e4.x); b.y = f2b(e4.y); b.z = f2b(e4.z); b.w = f2b(e4.w);
  reinterpret_cast<ushort4*>(embB)[n * 64 + lane] = b;
  if (blockIdx.x == 0) {
#pragma unroll
    for (int j = 0; j < 4; ++j) counts[tid + j * 256] = 0u;
  }
}

// ---------------------------------------------------------------- kernel B
// Fused argmin + loss + histogram + gather-out.
// D[code][xrow] = Emb . X^T via mfma_32x32x16_bf16, acc init = -||e||^2/2,
// argmin(dist) == argmax(acc); loss_row = ||x||^2 - 2*max(acc).
// Wave holds 64 x-rows in registers (2 fragments of 32); block = 4 waves =
// 256 rows; grid = 256 (1 block/CU). Emb streams as [64 codes][128 k] bf16
// half-chunks via global_load_lds (linear LDS dest, XOR-swizzled SOURCE
// granule; reads apply the same XOR). Epilogue gathers out = Emb[idx].
__global__ __launch_bounds__(256, 1) void vq_fused(
    const float* __restrict__ X, const float* __restrict__ Emb,
    const ushort* __restrict__ embB, const float* __restrict__ en2h,
    float* __restrict__ out, unsigned* __restrict__ counts,
    double* __restrict__ loss_part) {
  __shared__ ushort lds[2][64 * 128];   // 2 x 16 KiB half-chunks
  __shared__ int   idxLds[256];
  __shared__ float shl[4];
  const int tid = threadIdx.x;
  const int w   = tid >> 6;
  const int l   = tid & 63;
  const int col = l & 31;    // xrow within fragment / code within cf-tile
  const int khi = l >> 5;    // which 8-wide k sub-block of 16
  const int m0  = blockIdx.x * 256;
  const float4* __restrict__ embB4 = reinterpret_cast<const float4*>(embB);

  // per-lane swizzled SOURCE granule (16B units) within one [64][16] half
  int srcg[4];
#pragma unroll
  for (int c = 0; c < 4; ++c) {
    const int gi  = w * 256 + c * 64 + l;    // linear LDS granule this lane fills
    const int row = gi >> 4, gc = gi & 15;
    srcg[c] = row * 32 + (gc ^ (row & 15));  // embB4 granules: 32 per code row
  }
  auto issueHalf = [&](int b, int nt, int kh) {
#pragma unroll
    for (int c = 0; c < 4; ++c)
      gl_lds16(&embB4[nt * 2048 + kh * 16 + srcg[c]],
               &lds[b][(w * 256 + c * 64) * 8]);
  };

  // prefetch chunk 0 (both halves) before the long X prologue
  issueHalf(0, 0, 0);
  issueHalf(1, 0, 1);

  // X prologue: read once, ||x||^2 (per k-half), pack bf16 B-fragments.
  // fragment f: xrow = m0 + w*64 + f*32 + col; k = kb*16 + khi*8 .. +8
  bf16x8 xf0[16], xf1[16];
  float sx0 = 0.f, sx1 = 0.f;
  {
    const float* r0 = X + (size_t)(m0 + w * 64 + col) * 256 + khi * 8;
    const float* r1 = r0 + 32 * 256;
#pragma unroll
    for (int kb = 0; kb < 16; ++kb) {
      const float4 a = *reinterpret_cast<const float4*>(r0 + kb * 16);
      const float4 b = *reinterpret_cast<const float4*>(r0 + kb * 16 + 4);
      sx0 += a.x * a.x + a.y * a.y + a.z * a.z + a.w * a.w +
             b.x * b.x + b.y * b.y + b.z * b.z + b.w * b.w;
      bf16x8 v;
      v[0] = (short)f2b(a.x); v[1] = (short)f2b(a.y);
      v[2] = (short)f2b(a.z); v[3] = (short)f2b(a.w);
      v[4] = (short)f2b(b.x); v[5] = (short)f2b(b.y);
      v[6] = (short)f2b(b.z); v[7] = (short)f2b(b.w);
      xf0[kb] = v;
      const float4 c = *reinterpret_cast<const float4*>(r1 + kb * 16);
      const float4 d = *reinterpret_cast<const float4*>(r1 + kb * 16 + 4);
      sx1 += c.x * c.x + c.y * c.y + c.z * c.z + c.w * c.w +
             d.x * d.x + d.y * d.y + d.z * d.z + d.w * d.w;
      bf16x8 u;
      u[0] = (short)f2b(c.x); u[1] = (short)f2b(c.y);
      u[2] = (short)f2b(c.z); u[3] = (short)f2b(c.w);
      u[4] = (short)f2b(d.x); u[5] = (short)f2b(d.y);
      u[6] = (short)f2b(d.z); u[7] = (short)f2b(d.w);
      xf1[kb] = u;
    }
  }
  __syncthreads();   // chunk-0 halves landed; all waves ready

  float bv0 = -3.4e38f, bv1 = -3.4e38f;
  int   bi0 = 0, bi1 = 0;
  const int xsw = (col & 15);   // read-side XOR (row&15; +32 doesn't change it)

  for (int nt = 0; nt < 16; ++nt) {
    // acc init = -||e||^2/2: reg q of C holds code (q&3)+8*(q>>2)+4*khi (+cf*32)
    f32x16 acc00, acc01, acc10, acc11;   // [cf][fx]
#pragma unroll
    for (int g = 0; g < 4; ++g) {
      const f32x4 t0 =
          *reinterpret_cast<const f32x4*>(en2h + nt * 64 + khi * 4 + g * 8);
      const f32x4 t1 =
          *reinterpret_cast<const f32x4*>(en2h + nt * 64 + 32 + khi * 4 + g * 8);
#pragma unroll
      for (int j = 0; j < 4; ++j) {
        acc00[g * 4 + j] = t0[j]; acc01[g * 4 + j] = t0[j];
        acc10[g * 4 + j] = t1[j]; acc11[g * 4 + j] = t1[j];
      }
    }
    // ---- half 0: lds[0] (k 0..127)
#pragma unroll
    for (int kb = 0; kb < 8; ++kb) {
      const int gk = kb * 2 + khi;
      const bf16x8 a0 = *reinterpret_cast<const bf16x8*>(
          &lds[0][col * 128 + ((gk ^ xsw) * 8)]);
      const bf16x8 a1 = *reinterpret_cast<const bf16x8*>(
          &lds[0][(32 + col) * 128 + ((gk ^ xsw) * 8)]);
      acc00 = __builtin_amdgcn_mfma_f32_32x32x16_bf16(a0, xf0[kb], acc00, 0, 0, 0);
      acc01 = __builtin_amdgcn_mfma_f32_32x32x16_bf16(a0, xf1[kb], acc01, 0, 0, 0);
      acc10 = __builtin_amdgcn_mfma_f32_32x32x16_bf16(a1, xf0[kb], acc10, 0, 0, 0);
      acc11 = __builtin_amdgcn_mfma_f32_32x32x16_bf16(a1, xf1[kb], acc11, 0, 0, 0);
    }
    __syncthreads();                       // lds[0] consumed; next-half landed
    if (nt < 15) issueHalf(0, nt + 1, 0);  // prefetch under half-1 compute
    // ---- half 1: lds[1] (k 128..255)
#pragma unroll
    for (int kb = 0; kb < 8; ++kb) {
      const int gk = kb * 2 + khi;
      const bf16x8 a0 = *reinterpret_cast<const bf16x8*>(
          &lds[1][col * 128 + ((gk ^ xsw) * 8)]);
      const bf16x8 a1 = *reinterpret_cast<const bf16x8*>(
          &lds[1][(32 + col) * 128 + ((gk ^ xsw) * 8)]);
      acc00 = __builtin_amdgcn_mfma_f32_32x32x16_bf16(a0, xf0[8 + kb], acc00, 0, 0, 0);
      acc01 = __builtin_amdgcn_mfma_f32_32x32x16_bf16(a0, xf1[8 + kb], acc01, 0, 0, 0);
      acc10 = __builtin_amdgcn_mfma_f32_32x32x16_bf16(a1, xf0[8 + kb], acc10, 0, 0, 0);
      acc11 = __builtin_amdgcn_mfma_f32_32x32x16_bf16(a1, xf1[8 + kb], acc11, 0, 0, 0);
    }
    // fold into running argmax (codes ascending; strict > keeps first index)
#pragma unroll
    for (int q = 0; q < 16; ++q) {
      const int code = nt * 64 + (q & 3) + 8 * (q >> 2) + 4 * khi;
      if (acc00[q] > bv0) { bv0 = acc00[q]; bi0 = code; }
      if (acc01[q] > bv1) { bv1 = acc01[q]; bi1 = code; }
    }
#pragma unroll
    for (int q = 0; q < 16; ++q) {
      const int code = nt * 64 + 32 + (q & 3) + 8 * (q >> 2) + 4 * khi;
      if (acc10[q] > bv0) { bv0 = acc10[q]; bi0 = code; }
      if (acc11[q] > bv1) { bv1 = acc11[q]; bi1 = code; }
    }
    __syncthreads();                       // lds[1] consumed
    if (nt < 15) issueHalf(1, nt + 1, 1);  // prefetch under next half-0
  }

  // merge khi halves (lanes l and l^32 hold same xrow, different codes/k)
  sx0 += __shfl_xor(sx0, 32, 64);
  sx1 += __shfl_xor(sx1, 32, 64);
  {
    const float ov = __shfl_xor(bv0, 32, 64);
    const int   oi = __shfl_xor(bi0, 32, 64);
    if (ov > bv0 || (ov == bv0 && oi < bi0)) { bv0 = ov; bi0 = oi; }
  }
  {
    const float ov = __shfl_xor(bv1, 32, 64);
    const int   oi = __shfl_xor(bi1, 32, 64);
    if (ov > bv1 || (ov == bv1 && oi < bi1)) { bv1 = ov; bi1 = oi; }
  }
  float lloss = 0.f;
  if (l < 32) {
    idxLds[w * 64 + col]      = bi0;
    idxLds[w * 64 + 32 + col] = bi1;
    atomicAdd(&counts[bi0], 1u);
    atomicAdd(&counts[bi1], 1u);
    lloss = (sx0 - 2.f * bv0) + (sx1 - 2.f * bv1);
  }
#pragma unroll
  for (int off = 1; off < 64; off <<= 1) lloss += __shfl_xor(lloss, off, 64);
  if (l == 0) shl[w] = lloss;
  __syncthreads();
  if (tid == 0)
    loss_part[blockIdx.x] =
        (double)(shl[0] + shl[1] + shl[2] + shl[3]);

  // gather epilogue: out = Emb[idx] (exact f32 rows), wave-uniform Emb row
  const float4* __restrict__ Emb4 = reinterpret_cast<const float4*>(Emb);
  float4* __restrict__ out4 = reinterpret_cast<float4*>(out);
  const int oc = tid & 63;
  const int rg = tid >> 6;
#pragma unroll 8
  for (int i = 0; i < 64; ++i) {
    const int r  = i * 4 + rg;
    const int cc = idxLds[r];
    out4[(size_t)(m0 + r) * 64 + oc] = Emb4[cc * 64 + oc];
  }
}

// ---------------------------------------------------------------- kernel C
// loss = 1.25 * sum(loss_part)/16.7M; perplexity = exp(-sum p log(p+1e-10))
__global__ __launch_bounds__(1024) void vq_final(
    const unsigned* __restrict__ counts, const double* __restrict__ loss_part,
    float* __restrict__ out) {
  const int tid = threadIdx.x;  // 1024 threads
  const double p = (double)counts[tid] * (1.0 / 65536.0);
  double term = -p * log(p + 1e-10);
  double lp = (tid < 256) ? loss_part[tid] : 0.0;
#pragma unroll
  for (int m = 1; m < 64; m <<= 1) {
    term += __shfl_xor(term, m, 64);
    lp   += __shfl_xor(lp, m, 64);
  }
  __shared__ double sh[16], sl[16];
  if ((tid & 63) == 0) { sh[tid >> 6] = term; sl[tid >> 6] = lp; }
  __syncthreads();
  if (tid == 0) {
    double H = 0.0, L = 0.0;
#pragma unroll
    for (int i = 0; i < 16; ++i) { H += sh[i]; L += sl[i]; }
    out[16777216] = (float)(1.25 * L * (1.0 / 16777216.0));
    out[16777217] = (float)exp(H);
  }
}

// ---------------------------------------------------------------- launch
extern "C" void kernel_launch(void* const* d_in, const int* in_sizes, int n_in,
                              void* d_out, int out_size, void* d_ws, size_t ws_size,
                              hipStream_t stream) {
  const float* X   = (const float*)d_in[0];
  const float* Emb = (const float*)d_in[1];
  float* out = (float*)d_out;
  char* ws = (char*)d_ws;
  float*    en2h      = (float*)(ws);
  ushort*   embB      = (ushort*)(ws + 4096);
  unsigned* counts    = (unsigned*)(ws + 528384);
  double*   loss_part = (double*)(ws + 532480);

  vq_prep<<<256, 256, 0, stream>>>(Emb, en2h, embB, counts);
  vq_fused<<<256, 256, 0, stream>>>(X, Emb, embB, en2h, out, counts, loss_part);
  vq_final<<<1, 1024, 0, stream>>>(counts, loss_part, out);
}